// Round 2
// baseline (5652.284 us; speedup 1.0000x reference)
//
#include <hip/hip_runtime.h>
#include <math.h>

// Problem geometry (fixed by setup_inputs)
constexpr int Bb  = 8;
constexpr int Cc  = 192;   // y channels (== ch == dim)
constexpr int Hh  = 32;
constexpr int Ww  = 48;
constexpr int NS  = Bb * Hh * Ww;   // 12288 samples
constexpr int CIN = 384;            // merged channels (y + h_tilde)

#define LRELU(v) ((v) >= 0.0f ? (v) : 0.2f * (v))

// ---------------------------------------------------------------------------
// Prep: quantize y (eval-path STE round = floor(x+0.5), clipped to [-128,127])
// ---------------------------------------------------------------------------
__global__ void k_quant(const float* __restrict__ y, float* __restrict__ yq, int n) {
    int i = blockIdx.x * 256 + threadIdx.x;
    if (i < n) {
        float v = floorf(y[i] + 0.5f);
        yq[i] = fminf(fmaxf(v, -128.0f), 127.0f);
    }
}

// ---------------------------------------------------------------------------
// Weight transposes: [oc][ic][k] -> [ic][k][oc]  (wave-coalesced reads later)
// ---------------------------------------------------------------------------
__global__ void k_prep_w0(const float* __restrict__ w, float* __restrict__ wt) {
    int i = blockIdx.x * 256 + threadIdx.x;           // 192*384*9
    if (i >= 192 * 384 * 9) return;
    int k = i % 9; int ic = (i / 9) % 384; int oc = i / (9 * 384);
    wt[(ic * 9 + k) * 192 + oc] = w[i];
}
__global__ void k_prep_w192(const float* __restrict__ w, float* __restrict__ wt) {
    int i = blockIdx.x * 256 + threadIdx.x;           // 192*192*9
    if (i >= 192 * 192 * 9) return;
    int k = i % 9; int ic = (i / 9) % 192; int oc = i / (9 * 192);
    wt[(ic * 9 + k) * 192 + oc] = w[i];
}
__global__ void k_prep_fc(const float* __restrict__ w, float* __restrict__ wt) {
    int i = blockIdx.x * 256 + threadIdx.x;           // 384*768
    if (i >= 384 * 768) return;
    int f = i % 768; int o = i / 768;
    wt[f * 384 + o] = w[i];
}

// ---------------------------------------------------------------------------
// Stage 1: gather masked patches + conv0 (3x3, 384->192, pad 1, on 4x4)
//          + conv1 (3x3 stride 2, 192->192) -> t1[n][192][2][2]
// Block: 192 threads (thread = out-channel), 2 samples per block.
// ---------------------------------------------------------------------------
__global__ __launch_bounds__(192) void k_convAB(
    const float* __restrict__ yq, const float* __restrict__ ht,
    const float* __restrict__ w0t, const float* __restrict__ b0,
    const float* __restrict__ w1t, const float* __restrict__ b1,
    float* __restrict__ t1)
{
    __shared__ float patch[2][CIN][16];   // 48 KB
    __shared__ float t0[2][192][16];      // 24 KB
    const int tid = threadIdx.x;
    const int n0  = blockIdx.x * 2;

    // Gather: patch[s][ch][py*4+px] = src[b,ch,yy+py-3,xx+px-2] (0 outside),
    // masked (py==3 && px>=2) -> 0 for y channels only.
    for (int idx = tid; idx < 2 * CIN * 16; idx += 192) {
        int s   = idx / (CIN * 16);
        int rem = idx % (CIN * 16);
        int ch  = rem >> 4;
        int pp  = rem & 15;
        int py  = pp >> 2, px = pp & 3;
        int n   = n0 + s;
        int b   = n / (Hh * Ww);
        int r2  = n % (Hh * Ww);
        int yy  = r2 / Ww, xx = r2 % Ww;
        int gy  = yy + py - 3, gx = xx + px - 2;
        float v = 0.0f;
        bool inb = (gy >= 0 && gy < Hh && gx >= 0 && gx < Ww);
        if (ch < Cc) {
            if (inb && !(py == 3 && px >= 2))
                v = yq[((b * Cc + ch) * Hh + gy) * Ww + gx];
        } else {
            if (inb)
                v = ht[((b * Cc + (ch - Cc)) * Hh + gy) * Ww + gx];
        }
        patch[s][ch][pp] = v;
    }
    __syncthreads();

    const int oc = tid;

    // conv0: out[s][oc][oy][ox], pad 1 on the 4x4 patch
    float acc0[2][16];
    {
        float bias = b0[oc];
        #pragma unroll
        for (int s = 0; s < 2; ++s)
            #pragma unroll
            for (int p = 0; p < 16; ++p) acc0[s][p] = bias;
    }
    for (int ic = 0; ic < CIN; ++ic) {
        float wv[9];
        #pragma unroll
        for (int k = 0; k < 9; ++k) wv[k] = w0t[(ic * 9 + k) * 192 + oc];
        #pragma unroll
        for (int s = 0; s < 2; ++s) {
            float p[16];
            #pragma unroll
            for (int k = 0; k < 4; ++k) {
                float4 v = *reinterpret_cast<const float4*>(&patch[s][ic][k * 4]);
                p[k*4+0] = v.x; p[k*4+1] = v.y; p[k*4+2] = v.z; p[k*4+3] = v.w;
            }
            #pragma unroll
            for (int oy = 0; oy < 4; ++oy)
                #pragma unroll
                for (int ox = 0; ox < 4; ++ox) {
                    float a = acc0[s][oy * 4 + ox];
                    #pragma unroll
                    for (int ki = 0; ki < 3; ++ki) {
                        int py = oy + ki - 1;
                        if (py < 0 || py > 3) continue;
                        #pragma unroll
                        for (int kj = 0; kj < 3; ++kj) {
                            int px = ox + kj - 1;
                            if (px < 0 || px > 3) continue;
                            a = fmaf(wv[ki * 3 + kj], p[py * 4 + px], a);
                        }
                    }
                    acc0[s][oy * 4 + ox] = a;
                }
        }
    }
    #pragma unroll
    for (int s = 0; s < 2; ++s)
        #pragma unroll
        for (int p = 0; p < 16; ++p)
            t0[s][oc][p] = LRELU(acc0[s][p]);
    __syncthreads();

    // conv1: stride 2, pad 1, 4x4 -> 2x2
    float acc1[2][4];
    {
        float bias = b1[oc];
        #pragma unroll
        for (int s = 0; s < 2; ++s)
            #pragma unroll
            for (int q = 0; q < 4; ++q) acc1[s][q] = bias;
    }
    for (int ic = 0; ic < 192; ++ic) {
        float wv[9];
        #pragma unroll
        for (int k = 0; k < 9; ++k) wv[k] = w1t[(ic * 9 + k) * 192 + oc];
        #pragma unroll
        for (int s = 0; s < 2; ++s) {
            float p[16];
            #pragma unroll
            for (int k = 0; k < 4; ++k) {
                float4 v = *reinterpret_cast<const float4*>(&t0[s][ic][k * 4]);
                p[k*4+0] = v.x; p[k*4+1] = v.y; p[k*4+2] = v.z; p[k*4+3] = v.w;
            }
            #pragma unroll
            for (int qy = 0; qy < 2; ++qy)
                #pragma unroll
                for (int qx = 0; qx < 2; ++qx) {
                    float a = acc1[s][qy * 2 + qx];
                    #pragma unroll
                    for (int ki = 0; ki < 3; ++ki) {
                        int py = 2 * qy - 1 + ki;
                        if (py < 0 || py > 3) continue;
                        #pragma unroll
                        for (int kj = 0; kj < 3; ++kj) {
                            int px = 2 * qx - 1 + kj;
                            if (px < 0 || px > 3) continue;
                            a = fmaf(wv[ki * 3 + kj], p[py * 4 + px], a);
                        }
                    }
                    acc1[s][qy * 2 + qx] = a;
                }
        }
    }
    #pragma unroll
    for (int s = 0; s < 2; ++s) {
        float4 v;
        v.x = LRELU(acc1[s][0]); v.y = LRELU(acc1[s][1]);
        v.z = LRELU(acc1[s][2]); v.w = LRELU(acc1[s][3]);
        *reinterpret_cast<float4*>(&t1[((size_t)(n0 + s) * 192 + oc) * 4]) = v;
    }
}

// ---------------------------------------------------------------------------
// Stage 2: conv2 (3x3 pad 1 on 2x2) + FC (768->384) + Gaussian likelihood.
// Block: 384 threads, 4 samples per block.
// ---------------------------------------------------------------------------
__global__ __launch_bounds__(384) void k_tail(
    const float* __restrict__ t1, const float* __restrict__ w2t,
    const float* __restrict__ b2, const float* __restrict__ fcwt,
    const float* __restrict__ fcb, const float* __restrict__ yq,
    float* __restrict__ out)
{
    __shared__ float t1s[4][192][4];   // 12 KB
    __shared__ float t2s[4][768];      // 12 KB
    __shared__ float ctxs[4][384];     //  6 KB
    const int tid = threadIdx.x;
    const int n0  = blockIdx.x * 4;

    {   // load t1 for 4 samples (coalesced float4)
        const float4* src = reinterpret_cast<const float4*>(t1 + (size_t)n0 * 768);
        float4* dst = reinterpret_cast<float4*>(&t1s[0][0][0]);
        for (int i = tid; i < 768; i += 384) dst[i] = src[i];
    }
    __syncthreads();

    const int oc   = tid % 192;
    const int half = tid / 192;    // which pair of output positions

    float a2[4][2];
    {
        float bias = b2[oc];
        #pragma unroll
        for (int s = 0; s < 4; ++s) { a2[s][0] = bias; a2[s][1] = bias; }
    }
    for (int ic = 0; ic < 192; ++ic) {
        float wv[9];
        #pragma unroll
        for (int k = 0; k < 9; ++k) wv[k] = w2t[(ic * 9 + k) * 192 + oc];
        #pragma unroll
        for (int s = 0; s < 4; ++s) {
            float4 pv = *reinterpret_cast<const float4*>(&t1s[s][ic][0]);
            float p[4] = {pv.x, pv.y, pv.z, pv.w};
            #pragma unroll
            for (int o = 0; o < 2; ++o) {
                int q = half * 2 + o;
                int ry = q >> 1, rx = q & 1;
                float a = a2[s][o];
                #pragma unroll
                for (int ki = 0; ki < 3; ++ki) {
                    int py = ry - 1 + ki;
                    if (py < 0 || py > 1) continue;
                    #pragma unroll
                    for (int kj = 0; kj < 3; ++kj) {
                        int px = rx - 1 + kj;
                        if (px < 0 || px > 1) continue;
                        a = fmaf(wv[ki * 3 + kj], p[py * 2 + px], a);
                    }
                }
                a2[s][o] = a;
            }
        }
    }
    #pragma unroll
    for (int s = 0; s < 4; ++s)
        #pragma unroll
        for (int o = 0; o < 2; ++o) {
            int q = half * 2 + o;
            t2s[s][oc * 4 + q] = LRELU(a2[s][o]);   // flatten order ic*4 + ry*2 + rx
        }
    __syncthreads();

    // FC: ctx[s][o] = fcb[o] + sum_f t2s[s][f] * fc_w[o][f]
    {
        const int o = tid;   // 0..383
        float cacc[4];
        float cb = fcb[o];
        #pragma unroll
        for (int s = 0; s < 4; ++s) cacc[s] = cb;
        for (int f = 0; f < 768; ++f) {
            float wv = fcwt[f * 384 + o];
            #pragma unroll
            for (int s = 0; s < 4; ++s) cacc[s] = fmaf(wv, t2s[s][f], cacc[s]);
        }
        #pragma unroll
        for (int s = 0; s < 4; ++s) ctxs[s][o] = cacc[s];
    }
    __syncthreads();

    // Likelihood for 192 channels (threads 0..191)
    if (tid < 192) {
        const int cix = tid;
        #pragma unroll
        for (int s = 0; s < 4; ++s) {
            int n  = n0 + s;
            int b  = n / (Hh * Ww);
            int r2 = n % (Hh * Ww);
            int yy = r2 / Ww, xx = r2 % Ww;
            size_t gi = ((size_t)(b * Cc + cix) * Hh + yy) * Ww + xx;
            float q   = yq[gi];
            float mu  = ctxs[s][cix];
            float sg  = expf(ctxs[s][192 + cix]);
            float inv = 1.0f / sg;
            float up  = (q - mu + 0.5f) * inv;
            float lo  = (q - mu - 0.5f) * inv;
            const float k = 0.70710678118654752f;   // 1/sqrt(2)
            float like = 0.5f * erfcf(-up * k) - 0.5f * erfcf(-lo * k);
            out[gi] = fmaxf(like, 1e-12f);
        }
    }
}

// ---------------------------------------------------------------------------
extern "C" void kernel_launch(void* const* d_in, const int* in_sizes, int n_in,
                              void* d_out, int out_size, void* d_ws, size_t ws_size,
                              hipStream_t stream) {
    const float* y    = (const float*)d_in[0];
    const float* ht   = (const float*)d_in[1];
    const float* w0   = (const float*)d_in[2];
    const float* b0   = (const float*)d_in[3];
    const float* w1   = (const float*)d_in[4];
    const float* b1   = (const float*)d_in[5];
    const float* w2   = (const float*)d_in[6];
    const float* b2   = (const float*)d_in[7];
    const float* fcw  = (const float*)d_in[8];
    const float* fcb  = (const float*)d_in[9];
    float* out = (float*)d_out;

    // workspace layout (floats)
    float* ws   = (float*)d_ws;
    float* yq   = ws;                         // 2,359,296
    float* t1   = yq  + (size_t)Bb*Cc*Hh*Ww;  // 9,437,184
    float* w0t  = t1  + (size_t)NS*192*4;     // 663,552
    float* w1t  = w0t + 192*384*9;            // 331,776
    float* w2t  = w1t + 192*192*9;            // 331,776
    float* fcwt = w2t + 192*192*9;            // 294,912
    // total ~53.7 MB

    const int nq = Bb * Cc * Hh * Ww;
    k_quant<<<(nq + 255) / 256, 256, 0, stream>>>(y, yq, nq);
    k_prep_w0 <<<(192*384*9 + 255) / 256, 256, 0, stream>>>(w0, w0t);
    k_prep_w192<<<(192*192*9 + 255) / 256, 256, 0, stream>>>(w1, w1t);
    k_prep_w192<<<(192*192*9 + 255) / 256, 256, 0, stream>>>(w2, w2t);
    k_prep_fc <<<(384*768   + 255) / 256, 256, 0, stream>>>(fcw, fcwt);

    k_convAB<<<NS / 2, 192, 0, stream>>>(yq, ht, w0t, b0, w1t, b1, t1);
    k_tail  <<<NS / 4, 384, 0, stream>>>(t1, w2t, b2, fcwt, fcb, yq, out);
}

// Round 4
// 4380.621 us; speedup vs baseline: 1.2903x; 1.2903x over previous
//
#include <hip/hip_runtime.h>
#include <math.h>

// Problem geometry (fixed by setup_inputs)
constexpr int Bb   = 8;
constexpr int Cc   = 192;    // y channels (== ch == dim)
constexpr int Hh   = 32;
constexpr int Ww   = 48;
constexpr int NPIX = Hh * Ww;        // 1536 pixels per image
constexpr int NS   = Bb * NPIX;      // 12288 samples
constexpr int CIN  = 384;            // merged channels
constexpr int NF   = 9 * 192;        // 1728: (tap k, oc) columns, full 384-ic taps
constexpr int NY   = 6 * 192;        // 1152: (tap k6, oc) columns, y-only taps

#define LRELU(v) ((v) >= 0.0f ? (v) : 0.2f * (v))

// ---------------------------------------------------------------------------
// Quantize y: eval-path STE round = floor(x+0.5), clip [-128,127]
// ---------------------------------------------------------------------------
__global__ void k_quant(const float* __restrict__ y, float* __restrict__ yq, int n) {
    int i = blockIdx.x * 256 + threadIdx.x;
    if (i < n) {
        float v = floorf(y[i] + 0.5f);
        yq[i] = fminf(fmaxf(v, -128.0f), 127.0f);
    }
}

// ---------------------------------------------------------------------------
// Weight prep.
// w0n[ic][k*192+oc] = w0[oc][ic][k]      (k = ky*3+kx, 9 taps, ic<384)
// wyn[ic][k6*192+oc] = w0[oc][ic][k6+3]  (k6 -> taps ky in {1,2}, ic<192)
// w1t/w2t: [ic][k][oc];  fcwt: [f][o]
// ---------------------------------------------------------------------------
__global__ void k_prep_w0n(const float* __restrict__ w, float* __restrict__ wt) {
    int i = blockIdx.x * 256 + threadIdx.x;           // 384*1728
    if (i >= 384 * NF) return;
    int ic = i / NF; int rem = i % NF;
    int k = rem / 192; int oc = rem % 192;
    wt[i] = w[(oc * 384 + ic) * 9 + k];
}
__global__ void k_prep_wyn(const float* __restrict__ w, float* __restrict__ wt) {
    int i = blockIdx.x * 256 + threadIdx.x;           // 192*1152
    if (i >= 192 * NY) return;
    int ic = i / NY; int rem = i % NY;
    int k6 = rem / 192; int oc = rem % 192;
    wt[i] = w[(oc * 384 + ic) * 9 + (k6 + 3)];
}
__global__ void k_prep_w192(const float* __restrict__ w, float* __restrict__ wt) {
    int i = blockIdx.x * 256 + threadIdx.x;           // 192*192*9
    if (i >= 192 * 192 * 9) return;
    int k = i % 9; int ic = (i / 9) % 192; int oc = i / (9 * 192);
    wt[(ic * 9 + k) * 192 + oc] = w[i];
}
__global__ void k_prep_fc(const float* __restrict__ w, float* __restrict__ wt) {
    int i = blockIdx.x * 256 + threadIdx.x;           // 384*768
    if (i >= 384 * 768) return;
    int f = i % 768; int o = i / 768;
    wt[f * 384 + o] = w[i];
}

// ---------------------------------------------------------------------------
// H GEMM: C[pix][n] = sum_ic B[ic][pix] * A[ic][n]
//   B rows: ic<192 -> yq image, ic>=192 -> ht image (for y-only pass K=192).
//   Grid: (N/64, NPIX/64, images-in-chunk).  Block: 256 threads, 4x4 micro.
// ---------------------------------------------------------------------------
__global__ __launch_bounds__(256) void k_gemm(
    const float* __restrict__ A, const float* __restrict__ yqall,
    const float* __restrict__ htall, float* __restrict__ C,
    int K, int N, int img0)
{
    __shared__ float As[16][64];
    __shared__ float Bs[16][64];
    const int tid = threadIdx.x;
    const int tx = tid % 16, ty = tid / 16;
    const int n0 = blockIdx.x * 64, pix0 = blockIdx.y * 64;
    const int b = img0 + blockIdx.z;
    const float* yqb = yqall + (size_t)b * Cc * NPIX;
    const float* htb = htall + (size_t)b * Cc * NPIX;
    float* Cimg = C + (size_t)blockIdx.z * NPIX * N;

    float acc[4][4];
    #pragma unroll
    for (int i = 0; i < 4; ++i)
        #pragma unroll
        for (int j = 0; j < 4; ++j) acc[i][j] = 0.0f;

    const int r = tid / 16;          // staging row 0..15
    const int c4 = (tid % 16) * 4;   // staging col group

    for (int k0 = 0; k0 < K; k0 += 16) {
        {   // stage A and B tiles
            int ic = k0 + r;
            *reinterpret_cast<float4*>(&As[r][c4]) =
                *reinterpret_cast<const float4*>(&A[(size_t)ic * N + n0 + c4]);
            const float* brow = (ic < 192) ? (yqb + ic * NPIX)
                                           : (htb + (ic - 192) * NPIX);
            *reinterpret_cast<float4*>(&Bs[r][c4]) =
                *reinterpret_cast<const float4*>(&brow[pix0 + c4]);
        }
        __syncthreads();
        #pragma unroll
        for (int kk = 0; kk < 16; ++kk) {
            float4 bv = *reinterpret_cast<const float4*>(&Bs[kk][ty * 4]);
            float4 av = *reinterpret_cast<const float4*>(&As[kk][tx * 4]);
            float bb[4] = {bv.x, bv.y, bv.z, bv.w};
            float aa[4] = {av.x, av.y, av.z, av.w};
            #pragma unroll
            for (int mi = 0; mi < 4; ++mi)
                #pragma unroll
                for (int ni = 0; ni < 4; ++ni)
                    acc[mi][ni] = fmaf(bb[mi], aa[ni], acc[mi][ni]);
        }
        __syncthreads();
    }
    #pragma unroll
    for (int mi = 0; mi < 4; ++mi) {
        float4 v = {acc[mi][0], acc[mi][1], acc[mi][2], acc[mi][3]};
        *reinterpret_cast<float4*>(&Cimg[(size_t)(pix0 + ty * 4 + mi) * N + n0 + tx * 4]) = v;
    }
}

// ---------------------------------------------------------------------------
// Fused tail: t0 assembly from H (subset sums + mask corrections) + conv1 +
// conv2 + FC + likelihood.  Block: 384 threads, 4 samples.  Grid covers 2
// images (blockIdx.x = imgInChunk*384 + blk).
// ---------------------------------------------------------------------------
__global__ __launch_bounds__(384) void k_tail2(
    const float* __restrict__ yq,
    const float* __restrict__ Hf, const float* __restrict__ Hy,
    const float* __restrict__ b0v,
    const float* __restrict__ w1t, const float* __restrict__ b1,
    const float* __restrict__ w2t, const float* __restrict__ b2,
    const float* __restrict__ fcwt, const float* __restrict__ fcb,
    float* __restrict__ out, int img0)
{
    __shared__ float big[4][192][16];   // 48KB: t0s; later aliased as t2s+ctxs
    __shared__ float t1s[4][192][4];    // 12KB
    float* t2s  = &big[0][0][0];        // [4][768]
    float* ctxs = t2s + 4 * 768;        // [4][384]

    const int tid = threadIdx.x;
    const int bloc = blockIdx.x / 384;          // image within chunk
    const int blk  = blockIdx.x % 384;
    const int b    = img0 + bloc;
    const float* Hfb = Hf + (size_t)bloc * NPIX * NF;
    const float* Hyb = Hy + (size_t)bloc * NPIX * NY;

    const int oc = tid % 192;
    const int sh = tid / 192;    // 0/1 -> samples {0,1} / {2,3}

    // ---- Phase A: assemble t0 for this thread's 2 samples --------------
    for (int si = 0; si < 2; ++si) {
        const int s = sh * 2 + si;
        const int n_img = blk * 4 + s;
        const int y = n_img / Ww, x = n_img % Ww;
        float acc[16];
        {
            float bias = b0v[oc];
            #pragma unroll
            for (int p = 0; p < 16; ++p) acc[p] = bias;
        }
        #pragma unroll
        for (int py = 0; py < 4; ++py) {
            #pragma unroll
            for (int px = 0; px < 4; ++px) {
                int Y = y + py - 3, X = x + px - 2;
                if ((unsigned)Y < (unsigned)Hh && (unsigned)X < (unsigned)Ww) {
                    const int pix = Y * Ww + X;
                    const float* hp = Hfb + (size_t)pix * NF + oc;
                    // full-tap contributions: oy=py-dy, ox=px-dx in [0,3]
                    #pragma unroll
                    for (int dy = -1; dy <= 1; ++dy) {
                        int oy = py - dy;
                        if (oy < 0 || oy > 3) continue;
                        #pragma unroll
                        for (int dx = -1; dx <= 1; ++dx) {
                            int ox = px - dx;
                            if (ox < 0 || ox > 3) continue;
                            int k = (dy + 1) * 3 + (dx + 1);
                            acc[oy * 4 + ox] += hp[k * 192];
                        }
                    }
                    // y-mask corrections at patch (3,2) and (3,3)
                    if (py == 3 && px >= 2) {
                        const float* yp = Hyb + (size_t)pix * NY + oc;
                        #pragma unroll
                        for (int dy = 0; dy <= 1; ++dy) {
                            int oy = 3 - dy;   // py - dy
                            #pragma unroll
                            for (int dx = -1; dx <= 1; ++dx) {
                                int ox = px - dx;
                                if (ox < 0 || ox > 3) continue;
                                int k6 = dy * 3 + (dx + 1);
                                acc[oy * 4 + ox] -= yp[k6 * 192];
                            }
                        }
                    }
                }
            }
        }
        #pragma unroll
        for (int p = 0; p < 16; ++p) big[s][oc][p] = LRELU(acc[p]);
    }
    __syncthreads();

    // ---- Phase B: conv1 (3x3 stride 2, 4x4 -> 2x2) ----------------------
    {
        float acc1[2][4];
        float bias = b1[oc];
        #pragma unroll
        for (int si = 0; si < 2; ++si)
            #pragma unroll
            for (int q = 0; q < 4; ++q) acc1[si][q] = bias;
        for (int ic = 0; ic < 192; ++ic) {
            float wv[9];
            #pragma unroll
            for (int k = 0; k < 9; ++k) wv[k] = w1t[(ic * 9 + k) * 192 + oc];
            #pragma unroll
            for (int si = 0; si < 2; ++si) {
                const int s = sh * 2 + si;
                float p[16];
                #pragma unroll
                for (int k = 0; k < 4; ++k) {
                    float4 v = *reinterpret_cast<const float4*>(&big[s][ic][k * 4]);
                    p[k*4+0] = v.x; p[k*4+1] = v.y; p[k*4+2] = v.z; p[k*4+3] = v.w;
                }
                #pragma unroll
                for (int qy = 0; qy < 2; ++qy)
                    #pragma unroll
                    for (int qx = 0; qx < 2; ++qx) {
                        float a = acc1[si][qy * 2 + qx];
                        #pragma unroll
                        for (int ki = 0; ki < 3; ++ki) {
                            int py = 2 * qy - 1 + ki;
                            if (py < 0 || py > 3) continue;
                            #pragma unroll
                            for (int kj = 0; kj < 3; ++kj) {
                                int px = 2 * qx - 1 + kj;
                                if (px < 0 || px > 3) continue;
                                a = fmaf(wv[ki * 3 + kj], p[py * 4 + px], a);
                            }
                        }
                        acc1[si][qy * 2 + qx] = a;
                    }
            }
        }
        #pragma unroll
        for (int si = 0; si < 2; ++si) {
            const int s = sh * 2 + si;
            #pragma unroll
            for (int q = 0; q < 4; ++q) t1s[s][oc][q] = LRELU(acc1[si][q]);
        }
    }
    __syncthreads();   // conv1 done reading `big`; safe to alias as t2s/ctxs

    // ---- Phase C: conv2 (3x3 pad 1 on 2x2) ------------------------------
    {
        const int half = sh;   // which pair of output positions
        float a2[4][2];
        float bias = b2[oc];
        #pragma unroll
        for (int s = 0; s < 4; ++s) { a2[s][0] = bias; a2[s][1] = bias; }
        for (int ic = 0; ic < 192; ++ic) {
            float wv[9];
            #pragma unroll
            for (int k = 0; k < 9; ++k) wv[k] = w2t[(ic * 9 + k) * 192 + oc];
            #pragma unroll
            for (int s = 0; s < 4; ++s) {
                float4 pv = *reinterpret_cast<const float4*>(&t1s[s][ic][0]);
                float p[4] = {pv.x, pv.y, pv.z, pv.w};
                #pragma unroll
                for (int o = 0; o < 2; ++o) {
                    int q = half * 2 + o;
                    int ry = q >> 1, rx = q & 1;
                    float a = a2[s][o];
                    #pragma unroll
                    for (int ki = 0; ki < 3; ++ki) {
                        int py = ry - 1 + ki;
                        if (py < 0 || py > 1) continue;
                        #pragma unroll
                        for (int kj = 0; kj < 3; ++kj) {
                            int px = rx - 1 + kj;
                            if (px < 0 || px > 1) continue;
                            a = fmaf(wv[ki * 3 + kj], p[py * 2 + px], a);
                        }
                    }
                    a2[s][o] = a;
                }
            }
        }
        #pragma unroll
        for (int s = 0; s < 4; ++s)
            #pragma unroll
            for (int o = 0; o < 2; ++o) {
                int q = half * 2 + o;
                t2s[s * 768 + oc * 4 + q] = LRELU(a2[s][o]);
            }
    }
    __syncthreads();

    // ---- Phase D: FC 768 -> 384 -----------------------------------------
    {
        const int o = tid;   // 0..383
        float cacc[4];
        float cb = fcb[o];
        #pragma unroll
        for (int s = 0; s < 4; ++s) cacc[s] = cb;
        for (int f = 0; f < 768; ++f) {
            float wv = fcwt[f * 384 + o];
            #pragma unroll
            for (int s = 0; s < 4; ++s) cacc[s] = fmaf(wv, t2s[s * 768 + f], cacc[s]);
        }
        #pragma unroll
        for (int s = 0; s < 4; ++s) ctxs[s * 384 + o] = cacc[s];
    }
    __syncthreads();

    // ---- Phase E: Gaussian likelihood -----------------------------------
    if (tid < 192) {
        const int cix = tid;
        #pragma unroll
        for (int s = 0; s < 4; ++s) {
            const int n_img = blk * 4 + s;
            const int yy = n_img / Ww, xx = n_img % Ww;
            size_t gi = (((size_t)b * Cc + cix) * Hh + yy) * Ww + xx;
            float q   = yq[gi];
            float mu  = ctxs[s * 384 + cix];
            float sg  = expf(ctxs[s * 384 + 192 + cix]);
            float inv = 1.0f / sg;
            float up  = (q - mu + 0.5f) * inv;
            float lo  = (q - mu - 0.5f) * inv;
            const float kc = 0.70710678118654752f;   // 1/sqrt(2)
            float like = 0.5f * erfcf(-up * kc) - 0.5f * erfcf(-lo * kc);
            out[gi] = fmaxf(like, 1e-12f);
        }
    }
}

// ---------------------------------------------------------------------------
extern "C" void kernel_launch(void* const* d_in, const int* in_sizes, int n_in,
                              void* d_out, int out_size, void* d_ws, size_t ws_size,
                              hipStream_t stream) {
    const float* y    = (const float*)d_in[0];
    const float* ht   = (const float*)d_in[1];
    const float* w0   = (const float*)d_in[2];
    const float* b0   = (const float*)d_in[3];
    const float* w1   = (const float*)d_in[4];
    const float* b1   = (const float*)d_in[5];
    const float* w2   = (const float*)d_in[6];
    const float* b2   = (const float*)d_in[7];
    const float* fcw  = (const float*)d_in[8];
    const float* fcb  = (const float*)d_in[9];
    float* out = (float*)d_out;

    // workspace layout (floats) — total 13,049,856 fl = 52.2 MB (<53.7 proven)
    float* ws   = (float*)d_ws;
    float* yq   = ws;                             // 2,359,296
    float* Hf   = yq   + (size_t)Bb * Cc * NPIX;  // 2 imgs * 1536*1728 = 5,308,416
    float* Hy   = Hf   + (size_t)2 * NPIX * NF;   // 2 imgs * 1536*1152 = 3,538,944
    float* w0n  = Hy   + (size_t)2 * NPIX * NY;   // 663,552
    float* wyn  = w0n  + (size_t)384 * NF;        // 221,184
    float* w1t  = wyn  + (size_t)192 * NY;        // 331,776
    float* w2t  = w1t  + 192 * 192 * 9;           // 331,776
    float* fcwt = w2t  + 192 * 192 * 9;           // 294,912

    const int nq = Bb * Cc * Hh * Ww;
    k_quant   <<<(nq + 255) / 256, 256, 0, stream>>>(y, yq, nq);
    k_prep_w0n<<<(384 * NF + 255) / 256, 256, 0, stream>>>(w0, w0n);
    k_prep_wyn<<<(192 * NY + 255) / 256, 256, 0, stream>>>(w0, wyn);
    k_prep_w192<<<(192*192*9 + 255) / 256, 256, 0, stream>>>(w1, w1t);
    k_prep_w192<<<(192*192*9 + 255) / 256, 256, 0, stream>>>(w2, w2t);
    k_prep_fc <<<(384*768   + 255) / 256, 256, 0, stream>>>(fcw, fcwt);

    for (int img0 = 0; img0 < Bb; img0 += 2) {
        dim3 gf(NF / 64, NPIX / 64, 2);
        k_gemm<<<gf, 256, 0, stream>>>(w0n, yq, ht, Hf, 384, NF, img0);
        dim3 gy(NY / 64, NPIX / 64, 2);
        k_gemm<<<gy, 256, 0, stream>>>(wyn, yq, ht, Hy, 192, NY, img0);
        k_tail2<<<2 * 384, 384, 0, stream>>>(yq, Hf, Hy, b0, w1t, b1,
                                             w2t, b2, fcwt, fcb, out, img0);
    }
}

// Round 5
// 1206.067 us; speedup vs baseline: 4.6865x; 3.6322x over previous
//
#include <hip/hip_runtime.h>
#include <math.h>

// Problem geometry (fixed by setup_inputs)
constexpr int Bb   = 8;
constexpr int Cc   = 192;
constexpr int Hh   = 32;
constexpr int Ww   = 48;
constexpr int NPIX = Hh * Ww;        // 1536 pixels per image

#define LRELU(v) ((v) >= 0.0f ? (v) : 0.2f * (v))

// Per-z GEMM descriptors (conv1 has 4 different K's / offsets)
struct TD { int K[4]; int woff[4]; int rmoff[4]; int yoff[4]; };

// ---------------------------------------------------------------------------
// Quantize y -> bf16 bits (integers in [-128,127] are exact in bf16)
// ---------------------------------------------------------------------------
__global__ void k_quant(const float* __restrict__ y, unsigned short* __restrict__ yq, int n) {
    int i = blockIdx.x * 256 + threadIdx.x;
    if (i < n) {
        float v = floorf(y[i] + 0.5f);
        v = fminf(fmaxf(v, -128.0f), 127.0f);
        yq[i] = (unsigned short)(__float_as_uint(v) >> 16);
    }
}

// ---------------------------------------------------------------------------
// Weight prep kernels
// w0n[ic][k*192+oc] = w0[oc][ic][k]   (rows: ic 0..383, y-channels first)
// ---------------------------------------------------------------------------
__global__ void k_prep_w0n(const float* __restrict__ w, float* __restrict__ wt) {
    int i = blockIdx.x * 256 + threadIdx.x;           // 384*1728
    if (i >= 384 * 1728) return;
    int ic = i / 1728; int rem = i % 1728;
    int k = rem / 192; int oc = rem % 192;
    wt[i] = w[(oc * 384 + ic) * 9 + k];
}

// conv1 packed weights + rowmap.  25 slabs (pos lists per q), rows slab*192+ic.
__global__ void k_prep_w1p(const float* __restrict__ w, float* __restrict__ wp,
                           int* __restrict__ rowmap) {
    const int posflat[25] = {0,1,4,5, 1,2,3,5,6,7, 4,5,8,9,12,13,
                             5,6,7,9,10,11,13,14,15};
    int i = blockIdx.x * 256 + threadIdx.x;           // 25*192*192
    if (i >= 25 * 192 * 192) return;
    int slab = i / 36864; int rem = i % 36864;
    int ic = rem / 192; int oc = rem % 192;
    int q = (slab < 4) ? 0 : (slab < 10) ? 1 : (slab < 16) ? 2 : 3;
    int pos = posflat[slab];
    int py = pos >> 2, px = pos & 3;
    int ki = py - 2 * (q >> 1) + 1;
    int kj = px - 2 * (q & 1) + 1;
    wp[i] = w[(oc * 192 + ic) * 9 + ki * 3 + kj];
    if (oc == 0) rowmap[slab * 192 + ic] = pos * 192 + ic;
}

// conv2 packed: all 4 input positions used by every q.  rows (q,pos,ic).
__global__ void k_prep_w2p(const float* __restrict__ w, float* __restrict__ wp) {
    int i = blockIdx.x * 256 + threadIdx.x;           // 4*4*192*192
    if (i >= 4 * 4 * 192 * 192) return;
    int q = i / 147456; int rem = i % 147456;
    int pos = rem / 36864; int rem2 = rem % 36864;
    int ic = rem2 / 192; int oc = rem2 % 192;
    int ry = q >> 1, rx = q & 1;
    int py = pos >> 1, px = pos & 1;
    int ki = py - ry + 1, kj = px - rx + 1;           // always in [0,2]
    wp[i] = w[(oc * 192 + ic) * 9 + ki * 3 + kj];
}

// fc packed: row f' = q*192+oc  maps to original f = oc*4+q
__global__ void k_prep_fcp(const float* __restrict__ w, float* __restrict__ wp) {
    int i = blockIdx.x * 256 + threadIdx.x;           // 768*384
    if (i >= 768 * 384) return;
    int fp = i / 384; int o = i % 384;
    int q = fp / 192; int oc = fp % 192;
    wp[i] = w[o * 768 + oc * 4 + q];
}

// ---------------------------------------------------------------------------
// H GEMM: Hf[n][s] = sum_{ic<384} w0n[ic][n] * X[ic][s-col]
//   X rows: ic<192 -> yq (bf16 bits), else ht (fp32).  Snapshot after K=192
//   gives the y-only partials -> Hy (columns n in [576,1728)).
//   Grid (1728/64, S/64).  S = IMG*1536; each 64-col tile is in one image.
// ---------------------------------------------------------------------------
__global__ __launch_bounds__(256) void k_gemmH(
    const float* __restrict__ W, const unsigned short* __restrict__ yqall,
    const float* __restrict__ htall, float* __restrict__ Hf,
    float* __restrict__ Hy, int S, int img0)
{
    __shared__ float Ws[16][64];
    __shared__ float Xs[16][64];
    const int tid = threadIdx.x;
    const int tn = tid & 15, ts = tid >> 4;
    const int n0 = blockIdx.x * 64;
    const int s0 = blockIdx.y * 64;
    const int img = img0 + s0 / NPIX;
    const int pix0 = s0 % NPIX;
    const unsigned short* yqb = yqall + (size_t)img * (192 * NPIX);
    const float* htb = htall + (size_t)img * (192 * NPIX);
    const int r = ts, c4 = tn * 4;

    float acc[4][4] = {};
    float snap[4][4] = {};

    for (int k0 = 0; k0 < 384; k0 += 16) {
        if (k0 == 192) {
            #pragma unroll
            for (int i = 0; i < 4; ++i)
                #pragma unroll
                for (int j = 0; j < 4; ++j) snap[i][j] = acc[i][j];
        }
        const int ic = k0 + r;
        *reinterpret_cast<float4*>(&Ws[r][c4]) =
            *reinterpret_cast<const float4*>(&W[(size_t)ic * 1728 + n0 + c4]);
        if (ic < 192) {
            ushort4 u = *reinterpret_cast<const ushort4*>(&yqb[ic * NPIX + pix0 + c4]);
            Xs[r][c4 + 0] = __uint_as_float((unsigned)u.x << 16);
            Xs[r][c4 + 1] = __uint_as_float((unsigned)u.y << 16);
            Xs[r][c4 + 2] = __uint_as_float((unsigned)u.z << 16);
            Xs[r][c4 + 3] = __uint_as_float((unsigned)u.w << 16);
        } else {
            *reinterpret_cast<float4*>(&Xs[r][c4]) =
                *reinterpret_cast<const float4*>(&htb[(ic - 192) * NPIX + pix0 + c4]);
        }
        __syncthreads();
        #pragma unroll
        for (int kk = 0; kk < 16; ++kk) {
            float4 wv = *reinterpret_cast<const float4*>(&Ws[kk][tn * 4]);
            float4 xv = *reinterpret_cast<const float4*>(&Xs[kk][ts * 4]);
            float ww[4] = {wv.x, wv.y, wv.z, wv.w};
            float xx[4] = {xv.x, xv.y, xv.z, xv.w};
            #pragma unroll
            for (int ni = 0; ni < 4; ++ni)
                #pragma unroll
                for (int si = 0; si < 4; ++si)
                    acc[ni][si] = fmaf(ww[ni], xx[si], acc[ni][si]);
        }
        __syncthreads();
    }
    #pragma unroll
    for (int ni = 0; ni < 4; ++ni) {
        float4 v = {acc[ni][0], acc[ni][1], acc[ni][2], acc[ni][3]};
        *reinterpret_cast<float4*>(&Hf[(size_t)(n0 + tn * 4 + ni) * S + s0 + ts * 4]) = v;
    }
    if (n0 >= 576) {
        #pragma unroll
        for (int ni = 0; ni < 4; ++ni) {
            float4 v = {snap[ni][0], snap[ni][1], snap[ni][2], snap[ni][3]};
            *reinterpret_cast<float4*>(&Hy[(size_t)(n0 - 576 + tn * 4 + ni) * S + s0 + ts * 4]) = v;
        }
    }
}

// ---------------------------------------------------------------------------
// Tail GEMM: Y[n][s] = bias[n] + sum_k W[k][n] * X[row(k)][s], optional LRELU.
//   Per-z descriptors (conv1 q's).  All activation mats are [feat][S].
// ---------------------------------------------------------------------------
__global__ __launch_bounds__(256) void k_gemmT(
    const float* __restrict__ Wb, const float* __restrict__ X,
    float* __restrict__ Yb, const float* __restrict__ bias,
    const int* __restrict__ rowmap, int N, int S, int lrelu, TD d)
{
    __shared__ float Ws[16][64];
    __shared__ float Xs[16][64];
    const int z = blockIdx.z;
    const int K = d.K[z];
    const float* W = Wb + d.woff[z];
    float* Y = Yb + d.yoff[z];
    const int* rm = (d.rmoff[z] >= 0) ? (rowmap + d.rmoff[z]) : nullptr;

    const int tid = threadIdx.x;
    const int tn = tid & 15, ts = tid >> 4;
    const int n0 = blockIdx.x * 64;
    const int s0 = blockIdx.y * 64;
    const int r = ts, c4 = tn * 4;

    float acc[4][4] = {};

    for (int k0 = 0; k0 < K; k0 += 16) {
        const int k = k0 + r;
        *reinterpret_cast<float4*>(&Ws[r][c4]) =
            *reinterpret_cast<const float4*>(&W[(size_t)k * N + n0 + c4]);
        const int row = rm ? rm[k] : k;
        *reinterpret_cast<float4*>(&Xs[r][c4]) =
            *reinterpret_cast<const float4*>(&X[(size_t)row * S + s0 + c4]);
        __syncthreads();
        #pragma unroll
        for (int kk = 0; kk < 16; ++kk) {
            float4 wv = *reinterpret_cast<const float4*>(&Ws[kk][tn * 4]);
            float4 xv = *reinterpret_cast<const float4*>(&Xs[kk][ts * 4]);
            float ww[4] = {wv.x, wv.y, wv.z, wv.w};
            float xx[4] = {xv.x, xv.y, xv.z, xv.w};
            #pragma unroll
            for (int ni = 0; ni < 4; ++ni)
                #pragma unroll
                for (int si = 0; si < 4; ++si)
                    acc[ni][si] = fmaf(ww[ni], xx[si], acc[ni][si]);
        }
        __syncthreads();
    }

    float4 bv = *reinterpret_cast<const float4*>(&bias[n0 + tn * 4]);
    float bb[4] = {bv.x, bv.y, bv.z, bv.w};
    #pragma unroll
    for (int ni = 0; ni < 4; ++ni) {
        float v0 = acc[ni][0] + bb[ni];
        float v1 = acc[ni][1] + bb[ni];
        float v2 = acc[ni][2] + bb[ni];
        float v3 = acc[ni][3] + bb[ni];
        if (lrelu) { v0 = LRELU(v0); v1 = LRELU(v1); v2 = LRELU(v2); v3 = LRELU(v3); }
        float4 v = {v0, v1, v2, v3};
        *reinterpret_cast<float4*>(&Y[(size_t)(n0 + tn * 4 + ni) * S + s0 + ts * 4]) = v;
    }
}

// ---------------------------------------------------------------------------
// Assemble t0 from Hf/Hy: subset-sums of per-tap partials + mask corrections,
// bias + LRELU.  Block (64,4): 64 samples x 4 oc-lanes.  Grid (S/64, 48).
// t0[(pos*192+oc)][s]
// ---------------------------------------------------------------------------
__global__ __launch_bounds__(256) void k_asm(
    const float* __restrict__ Hf, const float* __restrict__ Hy,
    const float* __restrict__ b0, float* __restrict__ t0, int S)
{
    const int s  = blockIdx.x * 64 + threadIdx.x;
    const int oc = blockIdx.y * 4 + threadIdx.y;
    const int imgoff = (s / NPIX) * NPIX;
    const int p = s % NPIX;
    const int y = p / Ww, x = p % Ww;

    float acc[16];
    {
        float bias = b0[oc];
        #pragma unroll
        for (int i = 0; i < 16; ++i) acc[i] = bias;
    }
    #pragma unroll
    for (int py = 0; py < 4; ++py) {
        #pragma unroll
        for (int px = 0; px < 4; ++px) {
            int Y = y + py - 3, X = x + px - 2;
            if ((unsigned)Y < (unsigned)Hh && (unsigned)X < (unsigned)Ww) {
                const float* hp = Hf + (size_t)oc * S + imgoff + Y * Ww + X;
                #pragma unroll
                for (int dy = -1; dy <= 1; ++dy) {
                    int oy = py - dy; if (oy < 0 || oy > 3) continue;
                    #pragma unroll
                    for (int dx = -1; dx <= 1; ++dx) {
                        int ox = px - dx; if (ox < 0 || ox > 3) continue;
                        int k = (dy + 1) * 3 + (dx + 1);
                        acc[oy * 4 + ox] += hp[(size_t)k * 192 * S];
                    }
                }
            }
        }
    }
    // mask correction, patch (3,2): pixel = s itself (always in-bounds)
    {
        const float* yp = Hy + (size_t)oc * S + s;
        #pragma unroll
        for (int dy = 0; dy <= 1; ++dy)
            #pragma unroll
            for (int dx = -1; dx <= 1; ++dx) {
                int oy = 3 - dy, ox = 2 - dx;       // ox in {1,2,3}
                int k6 = dy * 3 + dx + 1;
                acc[oy * 4 + ox] -= yp[(size_t)k6 * 192 * S];
            }
    }
    // mask correction, patch (3,3): pixel = s+1 when x+1 < W
    if (x + 1 < Ww) {
        const float* yp = Hy + (size_t)oc * S + s + 1;
        #pragma unroll
        for (int dy = 0; dy <= 1; ++dy)
            #pragma unroll
            for (int dx = 0; dx <= 1; ++dx) {       // ox = 3-dx in {3,2}
                int oy = 3 - dy, ox = 3 - dx;
                int k6 = dy * 3 + dx + 1;
                acc[oy * 4 + ox] -= yp[(size_t)k6 * 192 * S];
            }
    }
    #pragma unroll
    for (int pos = 0; pos < 16; ++pos)
        t0[((size_t)pos * 192 + oc) * S + s] = LRELU(acc[pos]);
}

// ---------------------------------------------------------------------------
// Likelihood: ctx [384][S] -> out [B][192][1536]
// ---------------------------------------------------------------------------
__global__ void k_like(const float* __restrict__ ctx,
                       const unsigned short* __restrict__ yqall,
                       float* __restrict__ out, int S, int img0)
{
    int i = blockIdx.x * 256 + threadIdx.x;
    if (i >= 192 * S) return;
    int c = i / S, sc = i % S;
    int img = img0 + sc / NPIX;
    int p = sc % NPIX;
    float q  = __uint_as_float((unsigned)yqall[(size_t)img * (192 * NPIX) + c * NPIX + p] << 16);
    float mu = ctx[(size_t)c * S + sc];
    float sg = expf(ctx[(size_t)(192 + c) * S + sc]);
    float inv = 1.0f / sg;
    float up = (q - mu + 0.5f) * inv;
    float lo = (q - mu - 0.5f) * inv;
    const float kc = 0.70710678118654752f;
    float like = 0.5f * erfcf(-up * kc) - 0.5f * erfcf(-lo * kc);
    out[((size_t)img * 192 + c) * NPIX + p] = fmaxf(like, 1e-12f);
}

// ---------------------------------------------------------------------------
extern "C" void kernel_launch(void* const* d_in, const int* in_sizes, int n_in,
                              void* d_out, int out_size, void* d_ws, size_t ws_size,
                              hipStream_t stream) {
    const float* y    = (const float*)d_in[0];
    const float* ht   = (const float*)d_in[1];
    const float* w0   = (const float*)d_in[2];
    const float* b0   = (const float*)d_in[3];
    const float* w1   = (const float*)d_in[4];
    const float* b1   = (const float*)d_in[5];
    const float* w2   = (const float*)d_in[6];
    const float* b2   = (const float*)d_in[7];
    const float* fcw  = (const float*)d_in[8];
    const float* fcb  = (const float*)d_in[9];
    float* out = (float*)d_out;

    // ---- workspace layout (float units) ------------------------------------
    const size_t PERSIST = 3654336, PER_IMG = 9142272;
    int IMG = 1;
    if      (ws_size >= 4 * (PERSIST + 8 * PER_IMG)) IMG = 8;
    else if (ws_size >= 4 * (PERSIST + 4 * PER_IMG)) IMG = 4;
    else if (ws_size >= 4 * (PERSIST + 2 * PER_IMG)) IMG = 2;
    const int S = IMG * NPIX;

    float* ws = (float*)d_ws;
    unsigned short* yq16 = (unsigned short*)ws;         // 2,359,296 u16 = 1,179,648 fl
    float* w0n  = ws + 1179648;                         // 663,552
    float* w1p  = w0n + 663552;                         // 921,600
    float* w2p  = w1p + 921600;                         // 589,824
    float* fcp  = w2p + 589824;                         // 294,912
    int*   rmap = (int*)(fcp + 294912);                 // 4,800
    float* Hf   = ws + PERSIST;                         // IMG*1728*1536
    float* Hy   = Hf + (size_t)IMG * 1728 * NPIX;       // IMG*1152*1536
    float* t0   = Hy + (size_t)IMG * 1152 * NPIX;       // IMG*3072*1536
    float* t1   = Hy;                                   // IMG*768*1536 (alias)
    float* t2   = Hf;                                   // IMG*768*1536 (alias)
    float* ctx  = Hf + (size_t)768 * S;                 // IMG*384*1536 (alias)

    // ---- prep --------------------------------------------------------------
    const int nq = Bb * Cc * NPIX;
    k_quant   <<<(nq + 255) / 256, 256, 0, stream>>>(y, yq16, nq);
    k_prep_w0n<<<(384 * 1728 + 255) / 256, 256, 0, stream>>>(w0, w0n);
    k_prep_w1p<<<(25 * 192 * 192 + 255) / 256, 256, 0, stream>>>(w1, w1p, rmap);
    k_prep_w2p<<<(16 * 192 * 192 + 255) / 256, 256, 0, stream>>>(w2, w2p);
    k_prep_fcp<<<(768 * 384 + 255) / 256, 256, 0, stream>>>(fcw, fcp);

    // ---- per-z descriptors -------------------------------------------------
    TD dB, dC, dD;
    const int KB[4] = {768, 1152, 1152, 1728};
    const int wB[4] = {0, 147456, 368640, 589824};
    const int rB[4] = {0, 768, 1920, 3072};
    for (int q = 0; q < 4; ++q) {
        dB.K[q] = KB[q]; dB.woff[q] = wB[q]; dB.rmoff[q] = rB[q]; dB.yoff[q] = q * 192 * S;
        dC.K[q] = 768;   dC.woff[q] = q * 147456; dC.rmoff[q] = -1; dC.yoff[q] = q * 192 * S;
        dD.K[q] = 768;   dD.woff[q] = 0; dD.rmoff[q] = -1; dD.yoff[q] = 0;
    }

    // ---- main loop ---------------------------------------------------------
    for (int img0 = 0; img0 < Bb; img0 += IMG) {
        dim3 gH(27, S / 64);
        k_gemmH<<<gH, 256, 0, stream>>>(w0n, yq16, ht, Hf, Hy, S, img0);

        dim3 gA(S / 64, 48);
        k_asm<<<gA, dim3(64, 4), 0, stream>>>(Hf, Hy, b0, t0, S);

        dim3 gB(3, S / 64, 4);
        k_gemmT<<<gB, 256, 0, stream>>>(w1p, t0, t1, b1, rmap, 192, S, 1, dB);

        dim3 gC(3, S / 64, 4);
        k_gemmT<<<gC, 256, 0, stream>>>(w2p, t1, t2, b2, rmap, 192, S, 1, dC);

        dim3 gD(6, S / 64, 1);
        k_gemmT<<<gD, 256, 0, stream>>>(fcp, t2, ctx, fcb, rmap, 384, S, 0, dD);

        k_like<<<(192 * S + 255) / 256, 256, 0, stream>>>(ctx, yq16, out, S, img0);
    }
}

// Round 6
// 413.879 us; speedup vs baseline: 13.6568x; 2.9141x over previous
//
#include <hip/hip_runtime.h>
#include <math.h>

constexpr int Bb   = 8;
constexpr int Cc   = 192;
constexpr int Hh   = 32;
constexpr int Ww   = 48;
constexpr int NPIX = 1536;
constexpr int S    = 12288;          // total samples

typedef __attribute__((ext_vector_type(8))) short s16x8;   // 8 bf16 (4 VGPRs)
typedef __attribute__((ext_vector_type(4))) float f32x4;
typedef unsigned short u16;

#define LRELU(v) ((v) >= 0.0f ? (v) : 0.2f * (v))

__device__ __forceinline__ u16 f2b(float x) {
    __bf16 h = (__bf16)x;
    return *reinterpret_cast<u16*>(&h);
}

// ---------------------------------------------------------------------------
// Build XT[s][384] bf16: cols 0..191 = quantized y (exact), 192..383 = ht.
// 32x32 LDS transpose tiles; grid (48, 6, 16 = img*2+src), block (32,8).
// ---------------------------------------------------------------------------
__global__ __launch_bounds__(256) void k_quantT(
    const float* __restrict__ y, const float* __restrict__ ht,
    u16* __restrict__ XT)
{
    __shared__ float ld[32][33];
    const int tx = threadIdx.x, ty = threadIdx.y;
    const int p0 = blockIdx.x * 32, c0 = blockIdx.y * 32;
    const int img = blockIdx.z >> 1, src = blockIdx.z & 1;
    const float* sp = (src ? ht : y) + (size_t)img * 192 * NPIX;
    #pragma unroll
    for (int k = 0; k < 4; ++k) {
        float v = sp[(size_t)(c0 + ty + 8 * k) * NPIX + p0 + tx];
        if (!src) v = fminf(fmaxf(floorf(v + 0.5f), -128.0f), 127.0f);
        ld[ty + 8 * k][tx] = v;
    }
    __syncthreads();
    #pragma unroll
    for (int k = 0; k < 4; ++k)
        XT[((size_t)img * NPIX + p0 + ty + 8 * k) * 384 + src * 192 + c0 + tx] =
            f2b(ld[tx][ty + 8 * k]);
}

// ---------------------------------------------------------------------------
// Weight packs, all bf16 [n][K] row-major (contiguous k)
// ---------------------------------------------------------------------------
__global__ void k_prep_w0nk(const float* __restrict__ w, u16* __restrict__ wt) {
    int i = blockIdx.x * 256 + threadIdx.x;           // 1728*384
    if (i >= 1728 * 384) return;
    int n = i / 384, ic = i % 384;
    int k = n / 192, oc = n % 192;
    wt[i] = f2b(w[(oc * 384 + ic) * 9 + k]);
}
__global__ void k_prep_w1pk(const float* __restrict__ w, u16* __restrict__ wt) {
    const int posflat[25] = {0,1,4,5, 1,2,3,5,6,7, 4,5,8,9,12,13,
                             5,6,7,9,10,11,13,14,15};
    int i = blockIdx.x * 256 + threadIdx.x;           // 921600
    if (i >= 921600) return;
    int z, r, K, sbase;
    if      (i < 147456) { z = 0; r = i;          K = 768;  sbase = 0;  }
    else if (i < 368640) { z = 1; r = i - 147456; K = 1152; sbase = 4;  }
    else if (i < 589824) { z = 2; r = i - 368640; K = 1152; sbase = 10; }
    else                 { z = 3; r = i - 589824; K = 1728; sbase = 16; }
    int n = r / K, k = r % K;
    int slab = k / 192, ic = k % 192;
    int pos = posflat[sbase + slab];
    int py = pos >> 2, px = pos & 3;
    int ki = py - 2 * (z >> 1) + 1, kj = px - 2 * (z & 1) + 1;
    wt[i] = f2b(w[(n * 192 + ic) * 9 + ki * 3 + kj]);
}
__global__ void k_prep_w2pk(const float* __restrict__ w, u16* __restrict__ wt) {
    int i = blockIdx.x * 256 + threadIdx.x;           // 4*192*768
    if (i >= 589824) return;
    int z = i / 147456, r = i % 147456;
    int n = r / 768, k = r % 768;
    int pos = k / 192, ic = k % 192;
    int ki = (pos >> 1) - (z >> 1) + 1, kj = (pos & 1) - (z & 1) + 1;
    wt[i] = f2b(w[(n * 192 + ic) * 9 + ki * 3 + kj]);
}
__global__ void k_prep_fcpk(const float* __restrict__ w, u16* __restrict__ wt) {
    int i = blockIdx.x * 256 + threadIdx.x;           // 384*768
    if (i >= 384 * 768) return;
    int o = i / 768, fp = i % 768;
    int q = fp / 192, oc = fp % 192;
    wt[i] = f2b(w[o * 768 + oc * 4 + q]);
}

// ---------------------------------------------------------------------------
// H GEMM (MFMA): Hf[s][n] = sum_k XT[s][k]*W0[n][k], n = tap*192+oc (1728).
// Snapshot after k=192 -> Hy[s][n-576] (y-only partials for taps 3..8).
// Block 256 thr = 4 waves (2x2), tile 128(s) x 64(n), K_STEP 32.
// ---------------------------------------------------------------------------
__global__ __launch_bounds__(256) void k_hgemm(
    const u16* __restrict__ XT, const u16* __restrict__ W,
    float* __restrict__ Hf, float* __restrict__ Hy)
{
    __shared__ u16 As[128 * 40];   // 80B-padded rows
    __shared__ u16 Bs[64 * 40];
    const int tid = threadIdx.x;
    const int wave = tid >> 6, lane = tid & 63;
    const int wm = wave >> 1, wn = wave & 1;
    const int l15 = lane & 15, lk = lane >> 4;
    const int n0 = blockIdx.x * 64, s0 = blockIdx.y * 128;

    f32x4 acc[4][2], snap[4][2];
    #pragma unroll
    for (int a = 0; a < 4; ++a)
        #pragma unroll
        for (int b = 0; b < 2; ++b) { acc[a][b] = (f32x4){0,0,0,0}; snap[a][b] = (f32x4){0,0,0,0}; }

    for (int k0 = 0; k0 < 384; k0 += 32) {
        if (k0 == 192) {
            #pragma unroll
            for (int a = 0; a < 4; ++a)
                #pragma unroll
                for (int b = 0; b < 2; ++b) snap[a][b] = acc[a][b];
        }
        #pragma unroll
        for (int i = tid; i < 768; i += 256) {
            if (i < 512) {
                int row = i >> 2, c = i & 3;
                *reinterpret_cast<uint4*>(&As[row * 40 + c * 8]) =
                    *reinterpret_cast<const uint4*>(&XT[(size_t)(s0 + row) * 384 + k0 + c * 8]);
            } else {
                int j = i - 512, row = j >> 2, c = j & 3;
                *reinterpret_cast<uint4*>(&Bs[row * 40 + c * 8]) =
                    *reinterpret_cast<const uint4*>(&W[(size_t)(n0 + row) * 384 + k0 + c * 8]);
            }
        }
        __syncthreads();
        s16x8 af[4], bf[2];
        #pragma unroll
        for (int mi = 0; mi < 4; ++mi)
            af[mi] = *reinterpret_cast<const s16x8*>(&As[(wm * 64 + mi * 16 + l15) * 40 + lk * 8]);
        #pragma unroll
        for (int ni = 0; ni < 2; ++ni)
            bf[ni] = *reinterpret_cast<const s16x8*>(&Bs[(wn * 32 + ni * 16 + l15) * 40 + lk * 8]);
        #pragma unroll
        for (int mi = 0; mi < 4; ++mi)
            #pragma unroll
            for (int ni = 0; ni < 2; ++ni)
                acc[mi][ni] = __builtin_amdgcn_mfma_f32_16x16x32_bf16(af[mi], bf[ni], acc[mi][ni], 0, 0, 0);
        __syncthreads();
    }
    #pragma unroll
    for (int mi = 0; mi < 4; ++mi)
        #pragma unroll
        for (int r = 0; r < 4; ++r) {
            int srow = s0 + wm * 64 + mi * 16 + lk * 4 + r;
            #pragma unroll
            for (int ni = 0; ni < 2; ++ni) {
                int nc = n0 + wn * 32 + ni * 16 + l15;
                Hf[(size_t)srow * 1728 + nc] = acc[mi][ni][r];
                if (n0 >= 576) Hy[(size_t)srow * 1152 + nc - 576] = snap[mi][ni][r];
            }
        }
}

// ---------------------------------------------------------------------------
// Generic MFMA GEMM: Y[s][yoff+n] = act(bias[n0+n] + sum_k X[s][col(k)]*W[n][k])
//   col(k) = pm[k/192]*192 + k%192  (conv1 position gather; identity else)
//   mode 0: lrelu + bf16 store; mode 1: fp32 store, no lrelu
// ---------------------------------------------------------------------------
struct TDm { int K[4]; int woff[4]; int yoff[4]; int pm[4][9]; };

__global__ __launch_bounds__(256) void k_mgemm(
    const u16* __restrict__ X, int sx,
    const u16* __restrict__ Wb, const float* __restrict__ bias,
    void* __restrict__ Yb, int sy, int mode, TDm d)
{
    __shared__ u16 As[128 * 40];
    __shared__ u16 Bs[64 * 40];
    const int z = blockIdx.z;
    const int K = d.K[z];
    const u16* W = Wb + d.woff[z];
    const int tid = threadIdx.x;
    const int wave = tid >> 6, lane = tid & 63;
    const int wm = wave >> 1, wn = wave & 1;
    const int l15 = lane & 15, lk = lane >> 4;
    const int n0 = blockIdx.x * 64, s0 = blockIdx.y * 128;

    f32x4 acc[4][2];
    #pragma unroll
    for (int a = 0; a < 4; ++a)
        #pragma unroll
        for (int b = 0; b < 2; ++b) acc[a][b] = (f32x4){0,0,0,0};

    for (int k0 = 0; k0 < K; k0 += 32) {
        const int colA0 = d.pm[z][k0 / 192] * 192 + (k0 % 192);
        #pragma unroll
        for (int i = tid; i < 768; i += 256) {
            if (i < 512) {
                int row = i >> 2, c = i & 3;
                *reinterpret_cast<uint4*>(&As[row * 40 + c * 8]) =
                    *reinterpret_cast<const uint4*>(&X[(size_t)(s0 + row) * sx + colA0 + c * 8]);
            } else {
                int j = i - 512, row = j >> 2, c = j & 3;
                *reinterpret_cast<uint4*>(&Bs[row * 40 + c * 8]) =
                    *reinterpret_cast<const uint4*>(&W[(size_t)(n0 + row) * K + k0 + c * 8]);
            }
        }
        __syncthreads();
        s16x8 af[4], bf[2];
        #pragma unroll
        for (int mi = 0; mi < 4; ++mi)
            af[mi] = *reinterpret_cast<const s16x8*>(&As[(wm * 64 + mi * 16 + l15) * 40 + lk * 8]);
        #pragma unroll
        for (int ni = 0; ni < 2; ++ni)
            bf[ni] = *reinterpret_cast<const s16x8*>(&Bs[(wn * 32 + ni * 16 + l15) * 40 + lk * 8]);
        #pragma unroll
        for (int mi = 0; mi < 4; ++mi)
            #pragma unroll
            for (int ni = 0; ni < 2; ++ni)
                acc[mi][ni] = __builtin_amdgcn_mfma_f32_16x16x32_bf16(af[mi], bf[ni], acc[mi][ni], 0, 0, 0);
        __syncthreads();
    }
    #pragma unroll
    for (int mi = 0; mi < 4; ++mi)
        #pragma unroll
        for (int r = 0; r < 4; ++r) {
            int srow = s0 + wm * 64 + mi * 16 + lk * 4 + r;
            #pragma unroll
            for (int ni = 0; ni < 2; ++ni) {
                int nc = n0 + wn * 32 + ni * 16 + l15;
                float v = acc[mi][ni][r] + bias[nc];
                if (mode == 0) {
                    v = LRELU(v);
                    ((u16*)Yb)[(size_t)srow * sy + d.yoff[z] + nc] = f2b(v);
                } else {
                    ((float*)Yb)[(size_t)srow * sy + d.yoff[z] + nc] = v;
                }
            }
        }
}

// ---------------------------------------------------------------------------
// Assemble t0[s][pos*192+oc] (bf16) from Hf/Hy partials + bias + lrelu.
// 192 threads (oc), 8 samples per block; XCD-chunked block swizzle for L2.
// ---------------------------------------------------------------------------
__global__ __launch_bounds__(192) void k_asm(
    const float* __restrict__ Hf, const float* __restrict__ Hy,
    const float* __restrict__ b0, u16* __restrict__ t0)
{
    const int cpx = gridDim.x >> 3;   // 1536/8 = 192, exact
    const int bid = (blockIdx.x & 7) * cpx + (blockIdx.x >> 3);
    const int oc = threadIdx.x;
    const float bias = b0[oc];
    for (int si = 0; si < 8; ++si) {
        const int s = bid * 8 + si;
        const int imgbase = (s / NPIX) * NPIX;
        const int p = s % NPIX;
        const int yy = p / Ww, xx = p % Ww;
        float acc[16];
        #pragma unroll
        for (int i = 0; i < 16; ++i) acc[i] = bias;
        #pragma unroll
        for (int py = 0; py < 4; ++py) {
            #pragma unroll
            for (int px = 0; px < 4; ++px) {
                int Y = yy + py - 3, X = xx + px - 2;
                if ((unsigned)Y < (unsigned)Hh && (unsigned)X < (unsigned)Ww) {
                    const float* hp = Hf + (size_t)(imgbase + Y * Ww + X) * 1728 + oc;
                    #pragma unroll
                    for (int dy = -1; dy <= 1; ++dy) {
                        int oy = py - dy; if (oy < 0 || oy > 3) continue;
                        #pragma unroll
                        for (int dx = -1; dx <= 1; ++dx) {
                            int ox = px - dx; if (ox < 0 || ox > 3) continue;
                            acc[oy * 4 + ox] += hp[((dy + 1) * 3 + dx + 1) * 192];
                        }
                    }
                }
            }
        }
        {   // mask correction, patch (3,2): pixel = s (always in-bounds)
            const float* yp = Hy + (size_t)s * 1152 + oc;
            #pragma unroll
            for (int dy = 0; dy <= 1; ++dy)
                #pragma unroll
                for (int dx = -1; dx <= 1; ++dx)
                    acc[(3 - dy) * 4 + (2 - dx)] -= yp[(dy * 3 + dx + 1) * 192];
        }
        if (xx + 1 < Ww) {   // mask correction, patch (3,3): pixel = s+1
            const float* yp = Hy + (size_t)(s + 1) * 1152 + oc;
            #pragma unroll
            for (int dy = 0; dy <= 1; ++dy)
                #pragma unroll
                for (int dx = 0; dx <= 1; ++dx)
                    acc[(3 - dy) * 4 + (3 - dx)] -= yp[(dy * 3 + dx + 1) * 192];
        }
        u16* tr = t0 + (size_t)s * 3072 + oc;
        #pragma unroll
        for (int pos = 0; pos < 16; ++pos) tr[pos * 192] = f2b(LRELU(acc[pos]));
    }
}

// ---------------------------------------------------------------------------
// Likelihood into like[s][c] (coalesced), then transpose to out[b][c][p].
// ---------------------------------------------------------------------------
__global__ void k_like(const float* __restrict__ ctx, const u16* __restrict__ XT,
                       float* __restrict__ like)
{
    int i = blockIdx.x * 256 + threadIdx.x;
    if (i >= 192 * S) return;
    int s = i / 192, c = i % 192;
    u16 qb = XT[(size_t)s * 384 + c];
    unsigned qu = (unsigned)qb << 16;
    float q  = __uint_as_float(qu);
    float mu = ctx[(size_t)s * 384 + c];
    float sg = expf(ctx[(size_t)s * 384 + 192 + c]);
    float inv = 1.0f / sg;
    float up = (q - mu + 0.5f) * inv;
    float lo = (q - mu - 0.5f) * inv;
    const float kc = 0.70710678118654752f;
    float lk = 0.5f * erfcf(-up * kc) - 0.5f * erfcf(-lo * kc);
    like[i] = fmaxf(lk, 1e-12f);
}

__global__ __launch_bounds__(256) void k_outT(
    const float* __restrict__ like, float* __restrict__ out)
{
    __shared__ float ld[32][33];
    const int tx = threadIdx.x, ty = threadIdx.y;
    const int p0 = blockIdx.x * 32, c0 = blockIdx.y * 32;
    const int img = blockIdx.z;
    #pragma unroll
    for (int k = 0; k < 4; ++k)
        ld[ty + 8 * k][tx] = like[((size_t)img * NPIX + p0 + ty + 8 * k) * 192 + c0 + tx];
    __syncthreads();
    #pragma unroll
    for (int k = 0; k < 4; ++k)
        out[((size_t)img * 192 + c0 + ty + 8 * k) * NPIX + p0 + tx] = ld[tx][ty + 8 * k];
}

// ---------------------------------------------------------------------------
extern "C" void kernel_launch(void* const* d_in, const int* in_sizes, int n_in,
                              void* d_out, int out_size, void* d_ws, size_t ws_size,
                              hipStream_t stream) {
    const float* y    = (const float*)d_in[0];
    const float* ht   = (const float*)d_in[1];
    const float* w0   = (const float*)d_in[2];
    const float* b0   = (const float*)d_in[3];
    const float* w1   = (const float*)d_in[4];
    const float* b1   = (const float*)d_in[5];
    const float* w2   = (const float*)d_in[6];
    const float* b2   = (const float*)d_in[7];
    const float* fcw  = (const float*)d_in[8];
    const float* fcb  = (const float*)d_in[9];
    float* out = (float*)d_out;

    // ---- workspace (byte offsets; total ~231.4 MB, ws proven >= 307 MB) ----
    char* ws = (char*)d_ws;
    u16*   XT   = (u16*)(ws);                          //  9,437,184 B
    u16*   w0nk = (u16*)(ws + 9437184);                //  1,327,104
    u16*   w1pk = (u16*)(ws + 10764288);               //  1,843,200
    u16*   w2pk = (u16*)(ws + 12607488);               //  1,179,648
    u16*   fcpk = (u16*)(ws + 13787136);               //    589,824
    float* Hf   = (float*)(ws + 14376960);             // 84,934,656
    float* Hy   = (float*)(ws + 99311616);             // 56,623,104
    u16*   t0   = (u16*)(ws + 155934720);              // 75,497,472 -> 231,432,192
    u16*   t1   = (u16*)Hy;                            // alias (Hy dead after asm)
    u16*   t2   = (u16*)(ws + 99311616 + 18874368);
    float* ctx  = Hf;                                  // alias (Hf dead after asm)
    float* like = (float*)(ws + 14376960 + 18874368);

    // ---- prep ----
    k_quantT<<<dim3(48, 6, 16), dim3(32, 8), 0, stream>>>(y, ht, XT);
    k_prep_w0nk<<<(1728 * 384 + 255) / 256, 256, 0, stream>>>(w0, w0nk);
    k_prep_w1pk<<<(921600 + 255) / 256, 256, 0, stream>>>(w1, w1pk);
    k_prep_w2pk<<<(589824 + 255) / 256, 256, 0, stream>>>(w2, w2pk);
    k_prep_fcpk<<<(384 * 768 + 255) / 256, 256, 0, stream>>>(fcw, fcpk);

    // ---- descriptors ----
    TDm dB = {}, dC = {}, dD = {};
    const int KB[4]   = {768, 1152, 1152, 1728};
    const int wB[4]   = {0, 147456, 368640, 589824};
    const int pmB[4][9] = {
        {0,1,4,5,0,0,0,0,0},
        {1,2,3,5,6,7,0,0,0},
        {4,5,8,9,12,13,0,0,0},
        {5,6,7,9,10,11,13,14,15}};
    for (int q = 0; q < 4; ++q) {
        dB.K[q] = KB[q]; dB.woff[q] = wB[q]; dB.yoff[q] = q * 192;
        for (int j = 0; j < 9; ++j) dB.pm[q][j] = pmB[q][j];
        dC.K[q] = 768; dC.woff[q] = q * 147456; dC.yoff[q] = q * 192;
        for (int j = 0; j < 4; ++j) dC.pm[q][j] = j;
        dD.K[q] = 768; dD.woff[q] = 0; dD.yoff[q] = 0;
        for (int j = 0; j < 4; ++j) dD.pm[q][j] = j;
    }

    // ---- pipeline ----
    k_hgemm<<<dim3(27, 96), 256, 0, stream>>>(XT, w0nk, Hf, Hy);
    k_asm<<<1536, 192, 0, stream>>>(Hf, Hy, b0, t0);
    k_mgemm<<<dim3(3, 96, 4), 256, 0, stream>>>(t0, 3072, w1pk, b1, t1, 768, 0, dB);
    k_mgemm<<<dim3(3, 96, 4), 256, 0, stream>>>(t1, 768, w2pk, b2, t2, 768, 0, dC);
    k_mgemm<<<dim3(6, 96, 1), 256, 0, stream>>>(t2, 768, fcpk, fcb, ctx, 384, 1, dD);
    k_like<<<(192 * S + 255) / 256, 256, 0, stream>>>(ctx, XT, like);
    k_outT<<<dim3(48, 6, 8), dim3(32, 8), 0, stream>>>(like, out);
}